// Round 2
// baseline (681.974 us; speedup 1.0000x reference)
//
#include <hip/hip_runtime.h>
#include <math.h>

// (B,T,D,H,O) = (1024, 512, 64, 64, 32)
#define BB 1024
#define TT 512
#define OO 32
#define MM 4               // batch rows per block
#define NBLK (BB/MM)       // 256 blocks -> all 256 CUs
#define NSUP 128           // supersteps of 4 timesteps; s = 0..NSUP inclusive

typedef __attribute__((ext_vector_type(8))) short short8;   // 8 bf16 (4 VGPRs)
typedef __attribute__((ext_vector_type(4))) float f32x4;    // MFMA C/D

#define MFMA __builtin_amdgcn_mfma_f32_16x16x32_bf16
#define LOG2E 1.4426950408889634f
#define K2    2.8853900817779268f   /* 2*log2(e) */

// Raw barrier: waits LDS ops only; global loads stay in flight.
#define BAR() asm volatile("s_waitcnt lgkmcnt(0)\n\ts_barrier" ::: "memory")

__device__ __forceinline__ float exp2f_(float x) {
#if __has_builtin(__builtin_amdgcn_exp2f)
    return __builtin_amdgcn_exp2f(x);
#else
    float r; asm("v_exp_f32 %0, %1" : "=v"(r) : "v"(x)); return r;
#endif
}

// fp32 -> bf16 RNE (one-time weight conversion)
__device__ __forceinline__ ushort f2bf(float f) {
    union { float f; unsigned u; } v; v.f = f;
    unsigned r = v.u + 0x7FFF + ((v.u >> 16) & 1);
    return (ushort)(r >> 16);
}
__device__ __forceinline__ float bf2f(ushort u) {
    union { unsigned u; float f; } v; v.u = ((unsigned)u) << 16; return v.f;
}
// pack two fp32 -> bf16x2 via v_perm (round-half-up)
__device__ __forceinline__ unsigned pkbf(float a, float b) {
    union { float f; unsigned u; } x, y; x.f = a; y.f = b;
    return __builtin_amdgcn_perm(y.u + 0x8000u, x.u + 0x8000u, 0x07060302u);
}
__device__ __forceinline__ short8 pack8(const float4& a, const float4& b) {
    union { unsigned u[4]; short8 s; } r;
    r.u[0] = pkbf(a.x, a.y); r.u[1] = pkbf(a.z, a.w);
    r.u[2] = pkbf(b.x, b.y); r.u[3] = pkbf(b.z, b.w);
    return r.s;
}

// ===========================================================================
// Row-per-wave LSTM. 8 waves/block: wv 0-3 = layer-0 for batch row wv;
// wv 4-7 = layer-1 for row wv-4 (lag 4 behind L0).
//
// Per wave, per step: recurrent part only (K=64), A-frag = h(t-1) broadcast
// into ALL 16 M-rows (rows duplicate; MFMA row R depends only on A row R, so
// output reg0 at quad q = real value). 16 output tiles (4 gates x 4 n-tiles)
// x 2 k-frags = 32 MFMA. Lane (q,l) needs only tiles (g, c==q), col l, reg0
// -> per-tile-group select keeps live acc at 16 regs.  h redistribution is a
// wave-private LDS row: write 1 ushort, lgkmcnt, broadcast ds_read_b128 --
// NO barrier in the recurrence.
//
// Cross-wave terms are precomputed per superstep (4 steps) in ONE coop phase
// (2 barriers / 4 steps):
//   pre0[t] = bias0 + x(t) @ W_ih0        (t in [4s, 4s+4))
//   pre1[t] = bias1 + h0(t) @ W_ih1       (t in [4(s-1), 4s), from h0 ring)
// M-packing: M-row m = 4*tau + row -> 16/16 real rows, 2 MFMA/tile, 16 tiles
// split over 8 waves = 2 tiles/wave. exp2 gate scales folded into all
// weights/biases (i,f,o: -log2e; g: +2log2e).
//
// h0 ring: [2 superstep-bufs][m=4*tau+row][64] bf16, XOR-swizzled
// (byte ^ ((m&7)<<4)) so the coop phase's strided A-frag reads spread banks.
// ===========================================================================
__global__ __launch_bounds__(512, 2)
void lstm_rw(const float* __restrict__ x,         // [B][T][64] fp32
             const float* __restrict__ w_ih0,     // [256][64]
             const float* __restrict__ w_hh0,     // [256][64]
             const float* __restrict__ b_ih0,     // [256]
             const float* __restrict__ b_hh0,     // [256]
             const float* __restrict__ w_ih1,     // [256][64]
             const float* __restrict__ w_hh1,     // [256][64]
             const float* __restrict__ b_ih1,     // [256]
             const float* __restrict__ b_hh1,     // [256]
             const float* __restrict__ fc_w,      // [32][64]
             const float* __restrict__ fc_b,      // [32]
             float* __restrict__ out)             // [B][32]
{
    // pre rings: [buf][tau][row][gate][unit] f32 (scaled, bias folded)
    __shared__ float  pre0r[2][4][4][4][64];      // 32 KB
    __shared__ float  pre1r[2][4][4][4][64];      // 32 KB
    __shared__ ushort h0r[2][16][64];             // 4 KB, swizzled rows
    __shared__ ushort h1b[2][4][64];              // 1 KB, wave-private rows

    const int tid  = threadIdx.x;
    const int wv   = tid >> 6;           // 0..7
    const bool gB  = (wv >= 4);          // layer-1 group
    const int r    = wv & 3;             // this wave's batch row
    const int ln   = tid & 63;
    const int l15  = ln & 15;
    const int quad = ln >> 4;
    const int b0   = blockIdx.x * MM;
    const int hq   = 16 * quad + l15;    // unit this lane owns in the cell

    // ---- recurrent weights (W_hh of this wave's layer) as 32 B-frags
    // bf[g][c][kt]: col = 64g+16c+l15, k = 32kt + 8*quad + j, scaled.
    const float* whh = gB ? w_hh1 : w_hh0;
    short8 bf[4][4][2];
#pragma unroll
    for (int g = 0; g < 4; ++g) {
        const float sc = (g == 2) ? K2 : -LOG2E;
#pragma unroll
        for (int c = 0; c < 4; ++c) {
            const int col = 64 * g + 16 * c + l15;
#pragma unroll
            for (int kt = 0; kt < 2; ++kt) {
                const float* src = whh + col * 64 + 32 * kt + 8 * quad;
                const float4 v0 = *(const float4*)src;
                const float4 v1 = *(const float4*)(src + 4);
                short8 b;
                b[0] = (short)f2bf(v0.x * sc); b[1] = (short)f2bf(v0.y * sc);
                b[2] = (short)f2bf(v0.z * sc); b[3] = (short)f2bf(v0.w * sc);
                b[4] = (short)f2bf(v1.x * sc); b[5] = (short)f2bf(v1.y * sc);
                b[6] = (short)f2bf(v1.z * sc); b[7] = (short)f2bf(v1.w * sc);
                bf[g][c][kt] = b;
            }
        }
    }

    // ---- coop-phase weights: 2 of 16 tiles per wave, for W_ih0 AND W_ih1
    const int tiA = 2 * wv, tiB = 2 * wv + 1;
    const int gA_ = tiA >> 2, cA_ = tiA & 3;
    const int gB_ = tiB >> 2, cB_ = tiB & 3;
    short8 wi0A[2], wi0B[2], wi1A[2], wi1B[2];
    float bias0A, bias0B, bias1A, bias1B;
    {
        const float scA = (gA_ == 2) ? K2 : -LOG2E;
        const float scB = (gB_ == 2) ? K2 : -LOG2E;
        const int colA = 64 * gA_ + 16 * cA_ + l15;
        const int colB = 64 * gB_ + 16 * cB_ + l15;
        bias0A = (b_ih0[colA] + b_hh0[colA]) * scA;
        bias0B = (b_ih0[colB] + b_hh0[colB]) * scB;
        bias1A = (b_ih1[colA] + b_hh1[colA]) * scA;
        bias1B = (b_ih1[colB] + b_hh1[colB]) * scB;
#pragma unroll
        for (int kt = 0; kt < 2; ++kt) {
            const int ko = 32 * kt + 8 * quad;
#define LDW(dst, W, col, sc)                                                  \
            { const float4 v0 = *(const float4*)(W + (col) * 64 + ko);        \
              const float4 v1 = *(const float4*)(W + (col) * 64 + ko + 4);    \
              short8 b;                                                       \
              b[0]=(short)f2bf(v0.x*(sc)); b[1]=(short)f2bf(v0.y*(sc));       \
              b[2]=(short)f2bf(v0.z*(sc)); b[3]=(short)f2bf(v0.w*(sc));       \
              b[4]=(short)f2bf(v1.x*(sc)); b[5]=(short)f2bf(v1.y*(sc));       \
              b[6]=(short)f2bf(v1.z*(sc)); b[7]=(short)f2bf(v1.w*(sc));       \
              dst = b; }
            LDW(wi0A[kt], w_ih0, colA, scA)
            LDW(wi0B[kt], w_ih0, colB, scB)
            LDW(wi1A[kt], w_ih1, colA, scA)
            LDW(wi1B[kt], w_ih1, colB, scB)
#undef LDW
        }
    }

    // zero h buffers (h(-1) = 0)
    for (int i = tid; i < 2 * 16 * 64; i += 512) ((ushort*)h0r)[i] = 0;
    for (int i = tid; i < 2 * 4 * 64; i += 512) ((ushort*)h1b)[i] = 0;

    // ---- x prefetch for coop phase: lane supplies A row m=l15 of the
    // M-packed x tile: (tau = l15>>2, row = l15&3), k = 8*quad+j (+32)
    const int xrr = l15 & 3, xtt = l15 >> 2;
    const size_t xbase = ((size_t)(b0 + xrr) * TT) * 64 + 8 * quad;
    float4 xp0, xp1, xp2, xp3;
    {
        const float* p = x + xbase + (size_t)xtt * 64;   // s = 0
        xp0 = *(const float4*)p;        xp1 = *(const float4*)(p + 4);
        xp2 = *(const float4*)(p + 32); xp3 = *(const float4*)(p + 36);
    }

    float cc = 0.f;                     // this lane's cell state
    const f32x4 z4 = (f32x4){0.f, 0.f, 0.f, 0.f};

// one cell from gate values y0..y3 (i,f,g,o scaled): 5 exp2 + 3 rcp
#define CELLH(LVAL)                                                           \
    {                                                                         \
        const float Ef = exp2f_(y1);                                         \
        const float Ei = exp2f_(y0);                                         \
        const float Eg = exp2f_(fminf(y2, 80.f));                            \
        const float sf = __builtin_amdgcn_rcpf(1.f + Ef);                    \
        const float rd = __builtin_amdgcn_rcpf((1.f + Ei) * (1.f + Eg));     \
        cc = sf * cc + (Eg - 1.f) * rd;                                      \
        const float Ec = exp2f_(fminf(cc * K2, 80.f));                       \
        const float Eo = exp2f_(y3);                                         \
        const float r2 = __builtin_amdgcn_rcpf((1.f + Eo) * (1.f + Ec));     \
        union { float f; unsigned u; } hv; hv.f = (Ec - 1.f) * r2;           \
        LVAL = (ushort)((hv.u + 0x8000u) >> 16);                             \
    }

// recurrent 32-MFMA block + per-tile-group select into y0..y3
#define RECUR(aa0, aa1)                                                       \
    _Pragma("unroll")                                                         \
    for (int c = 0; c < 4; ++c) {                                             \
        f32x4 A0 = MFMA(aa0, bf[0][c][0], z4, 0,0,0);                         \
        A0 = MFMA(aa1, bf[0][c][1], A0, 0,0,0);                               \
        f32x4 A1 = MFMA(aa0, bf[1][c][0], z4, 0,0,0);                         \
        A1 = MFMA(aa1, bf[1][c][1], A1, 0,0,0);                               \
        f32x4 A2 = MFMA(aa0, bf[2][c][0], z4, 0,0,0);                         \
        A2 = MFMA(aa1, bf[2][c][1], A2, 0,0,0);                               \
        f32x4 A3 = MFMA(aa0, bf[3][c][0], z4, 0,0,0);                         \
        A3 = MFMA(aa1, bf[3][c][1], A3, 0,0,0);                               \
        if (quad == c) { y0 += A0[0]; y1 += A1[0]; y2 += A2[0]; y3 += A3[0]; }\
    }

// coop tile: D = A*Wih + bias, scatter regs ri -> (tau=quad, row=ri)
#define COOPTILE(DST, A0_, A1_, W_, BV, G_, C_)                               \
    {                                                                         \
        f32x4 a = (f32x4){BV, BV, BV, BV};                                    \
        a = MFMA(A0_, W_[0], a, 0,0,0);                                       \
        a = MFMA(A1_, W_[1], a, 0,0,0);                                       \
        float* dst = &DST[cb][quad][0][G_][16 * (C_) + l15];                  \
        dst[0] = a[0]; dst[256] = a[1]; dst[512] = a[2]; dst[768] = a[3];     \
    }

    for (int s = 0; s <= NSUP; ++s) {
        BAR();                                  // h0 ring (prev buf) is final
        const int cb = s & 1, pb = cb ^ 1;

        // ---- coop phase -------------------------------------------------
        if (s < NSUP) {                         // pre0 for t in [4s, 4s+4)
            const short8 xlo = pack8(xp0, xp1);
            const short8 xhi = pack8(xp2, xp3);
            COOPTILE(pre0r, xlo, xhi, wi0A, bias0A, gA_, cA_)
            COOPTILE(pre0r, xlo, xhi, wi0B, bias0B, gB_, cB_)
        }
        if (s >= 1) {                           // pre1 for t in [4(s-1), 4s)
            const char* hb = (const char*)&h0r[pb][0][0];
            const int sw = (l15 & 7) << 4;
            const short8 hA0 = *(const short8*)(hb + l15 * 128 + ((16 * quad) ^ sw));
            const short8 hA1 = *(const short8*)(hb + l15 * 128 + ((64 + 16 * quad) ^ sw));
            COOPTILE(pre1r, hA0, hA1, wi1A, bias1A, gA_, cA_)
            COOPTILE(pre1r, hA0, hA1, wi1B, bias1B, gB_, cB_)
        }
        if (s + 1 < NSUP) {                     // prefetch x for phase s+1
            const float* p = x + xbase + (size_t)(4 * (s + 1) + xtt) * 64;
            xp0 = *(const float4*)p;        xp1 = *(const float4*)(p + 4);
            xp2 = *(const float4*)(p + 32); xp3 = *(const float4*)(p + 36);
        }
        BAR();                                  // pre rings ready

        // ---- 4 sequential steps, barrier-free ---------------------------
        if (!gB) {
            if (s < NSUP) {
#pragma unroll
                for (int tau = 0; tau < 4; ++tau) {
                    const int rb = (tau == 0) ? pb : cb;
                    const int m  = (tau == 0) ? (12 + r) : (4 * (tau - 1) + r);
                    const char* hb = (const char*)&h0r[rb][0][0];
                    const int sw = (m & 7) << 4;
                    const short8 a0 = *(const short8*)(hb + m * 128 + ((16 * quad) ^ sw));
                    const short8 a1 = *(const short8*)(hb + m * 128 + ((64 + 16 * quad) ^ sw));
                    const float* pp = &pre0r[cb][tau][r][0][hq];
                    float y0 = pp[0], y1 = pp[64], y2 = pp[128], y3 = pp[192];
                    RECUR(a0, a1)
                    const int mo = 4 * tau + r;
                    ushort hval; CELLH(hval)
                    *(ushort*)((char*)&h0r[cb][0][0] + mo * 128 +
                               ((2 * hq) ^ ((mo & 7) << 4))) = hval;
                }
            }
        } else {
            if (s >= 1) {
#pragma unroll
                for (int tau = 0; tau < 4; ++tau) {
                    const char* hb = (const char*)&h1b[(tau + 1) & 1][r][0];
                    const short8 a0 = *(const short8*)(hb + 16 * quad);
                    const short8 a1 = *(const short8*)(hb + 64 + 16 * quad);
                    const float* pp = &pre1r[cb][tau][r][0][hq];
                    float y0 = pp[0], y1 = pp[64], y2 = pp[128], y3 = pp[192];
                    RECUR(a0, a1)
                    ushort hval; CELLH(hval)
                    h1b[tau & 1][r][hq] = hval;
                }
            }
        }
    }
#undef COOPTILE
#undef RECUR
#undef CELLH

    BAR();
    // FC + softplus on h1(T-1) = h1b[1] (511 & 1 == 1); 128 outputs
    if (tid < MM * OO) {
        const int row = tid >> 5, o = tid & 31;
        float a = fc_b[o];
#pragma unroll
        for (int j = 0; j < 64; ++j)
            a = fmaf(fc_w[o * 64 + j], bf2f(h1b[1][row][j]), a);
        out[(size_t)(b0 + row) * OO + o] =
            fmaxf(a, 0.0f) + log1pf(__expf(-fabsf(a)));   // stable softplus
    }
}

extern "C" void kernel_launch(void* const* d_in, const int* in_sizes, int n_in,
                              void* d_out, int out_size, void* d_ws, size_t ws_size,
                              hipStream_t stream) {
    const float* x     = (const float*)d_in[0];
    const float* w_ih0 = (const float*)d_in[1];
    const float* w_hh0 = (const float*)d_in[2];
    const float* b_ih0 = (const float*)d_in[3];
    const float* b_hh0 = (const float*)d_in[4];
    const float* w_ih1 = (const float*)d_in[5];
    const float* w_hh1 = (const float*)d_in[6];
    const float* b_ih1 = (const float*)d_in[7];
    const float* b_hh1 = (const float*)d_in[8];
    const float* fc_w  = (const float*)d_in[9];
    const float* fc_b  = (const float*)d_in[10];
    float* out = (float*)d_out;

    lstm_rw<<<dim3(NBLK), dim3(512), 0, stream>>>(
        x, w_ih0, w_hh0, b_ih0, b_hh0,
        w_ih1, w_hh1, b_ih1, b_hh1, fc_w, fc_b, out);
}

// Round 3
// 472.861 us; speedup vs baseline: 1.4422x; 1.4422x over previous
//
#include <hip/hip_runtime.h>
#include <math.h>

// (B,T,D,H,O) = (1024, 512, 64, 64, 32)
#define BB 1024
#define TT 512
#define OO 32
#define MM 4               // batch rows per block
#define NBLK (BB/MM)       // 256 blocks -> all 256 CUs
#define SS 8               // timesteps per slot (between barriers)
#define NSLOT 66           // L0 active s=0..63, L1 active s=2..65

typedef __attribute__((ext_vector_type(8))) short short8;   // 8 bf16
typedef __attribute__((ext_vector_type(4))) float f32x4;    // MFMA C/D

#define MFMA __builtin_amdgcn_mfma_f32_16x16x32_bf16
#define LOG2E 1.4426950408889634f
#define K2    2.8853900817779268f   /* 2*log2(e) */

// Raw barrier: waits own LDS ops then rendezvous (global loads stay in flight)
#define BAR() asm volatile("s_waitcnt lgkmcnt(0)\n\ts_barrier" ::: "memory")

__device__ __forceinline__ float exp2f_(float x) {
#if __has_builtin(__builtin_amdgcn_exp2f)
    return __builtin_amdgcn_exp2f(x);
#else
    float r; asm("v_exp_f32 %0, %1" : "=v"(r) : "v"(x)); return r;
#endif
}

// fp32 -> bf16 RNE (one-time weight conversion)
__device__ __forceinline__ ushort f2bf(float f) {
    union { float f; unsigned u; } v; v.f = f;
    unsigned r = v.u + 0x7FFF + ((v.u >> 16) & 1);
    return (ushort)(r >> 16);
}
__device__ __forceinline__ float bf2f(ushort u) {
    union { unsigned u; float f; } v; v.u = ((unsigned)u) << 16; return v.f;
}
// pack two fp32 -> bf16x2 via v_perm (round-half-up)
__device__ __forceinline__ unsigned pkbf(float a, float b) {
    union { float f; unsigned u; } x, y; x.f = a; y.f = b;
    return __builtin_amdgcn_perm(y.u + 0x8000u, x.u + 0x8000u, 0x07060302u);
}
__device__ __forceinline__ short8 pack8(const float4& a, const float4& b) {
    union { unsigned u[4]; short8 s; } r;
    r.u[0] = pkbf(a.x, a.y); r.u[1] = pkbf(a.z, a.w);
    r.u[2] = pkbf(b.x, b.y); r.u[3] = pkbf(b.z, b.w);
    return r.s;
}

// ===========================================================================
// Producer-consumer LSTM. 4 waves / 256 threads / block, 256 blocks, 1 wave
// per SIMD (launch_bounds cap 512 VGPR -> NO spills; round-2's 50MB scratch
// WRITE_SIZE was the killer).
//
//   wv0 = L0 recurrence wave: all of W_hh0 in regs (32 short8 = 128 VGPR).
//   wv1 = L1 recurrence wave: W_hh1, lag-8 behind L0.
//   wv2/3 = coop waves: pre0 = b0 + x@W_ih0 (next slot) and
//           pre1 = b1 + h0@W_ih1 (prev slot, from h0 ring), 16-row M-packing
//           (4 steps x 4 rows), tiles split by n-block c.
//
// Recurrence per step (barrier-free, intra-wave): 4 rows M-packed at rows 4r
// (A row m <- h[m>>2]; MFMA row R depends only on A row R). Lane (q,l) reg0
// of tile (g,c) = (row q, unit 16c+l) -> gates read directly from
// accumulators; each lane runs 4 cells (units l,16+l,32+l,48+l of row q) and
// writes h to a bank-swizzled LDS ring (byte ^= 16*row -> 2-way max).
// ONE barrier per SS=8 steps: 513 -> 67 barriers.
//
// Ring disjointness per slot s (single barrier suffices):
//   pre0: L0 reads buf s&1,    coop writes buf (s+1)&1
//   pre1: L1 reads buf (s-2)&1, coop writes buf (s-1)&1
//   h0  : L0 writes slots [8s,8s+8)&15, coop reads [8s-8,8s)&15
// ===========================================================================
__global__ __launch_bounds__(256, 1)
void lstm_pc(const float* __restrict__ x,         // [B][T][64] fp32
             const float* __restrict__ w_ih0,     // [256][64]
             const float* __restrict__ w_hh0,     // [256][64]
             const float* __restrict__ b_ih0,     // [256]
             const float* __restrict__ b_hh0,     // [256]
             const float* __restrict__ w_ih1,     // [256][64]
             const float* __restrict__ w_hh1,     // [256][64]
             const float* __restrict__ b_ih1,     // [256]
             const float* __restrict__ b_hh1,     // [256]
             const float* __restrict__ fc_w,      // [32][64]
             const float* __restrict__ fc_b,      // [32]
             float* __restrict__ out)             // [B][32]
{
    // pre rings: [buf][tau][row][g][unit ^ 16*row] f32 (scaled, bias folded)
    __shared__ float  pre0[2][SS][4][4][64];      // 64 KB
    __shared__ float  pre1[2][SS][4][4][64];      // 64 KB
    // h rings: [slot][row][unit], 160B row stride, byte ^= 16*row swizzle
    __shared__ ushort h0u[16][4][80];             // 10 KB
    __shared__ ushort h1u[2][4][80];              // 1.25 KB

    const int tid = threadIdx.x;
    const int wv  = tid >> 6;            // 0..3
    const int ln  = tid & 63;
    const int l   = ln & 15;
    const int q   = ln >> 4;
    const int b0  = blockIdx.x * MM;
    const f32x4 z4 = (f32x4){0.f, 0.f, 0.f, 0.f};

    // zero h rings (h(-1) = 0)
    for (int i = tid; i < 16 * 4 * 80; i += 256) ((ushort*)h0u)[i] = 0;
    for (int i = tid; i < 2 * 4 * 80;  i += 256) ((ushort*)h1u)[i] = 0;

    if (wv < 2) {
        // ================= recurrence wave (layer wv) =================
        const float* whh = wv ? w_hh1 : w_hh0;
        short8 bf[4][4][2];              // [g][c][kt] full W_hh: 128 VGPR
#pragma unroll
        for (int g = 0; g < 4; ++g) {
            const float sc = (g == 2) ? K2 : -LOG2E;
#pragma unroll
            for (int c = 0; c < 4; ++c) {
                const int col = 64 * g + 16 * c + l;
#pragma unroll
                for (int kt = 0; kt < 2; ++kt) {
                    const float* src = whh + col * 64 + 32 * kt + 8 * q;
                    const float4 v0 = *(const float4*)src;
                    const float4 v1 = *(const float4*)(src + 4);
                    short8 b;
                    b[0] = (short)f2bf(v0.x * sc); b[1] = (short)f2bf(v0.y * sc);
                    b[2] = (short)f2bf(v0.z * sc); b[3] = (short)f2bf(v0.w * sc);
                    b[4] = (short)f2bf(v1.x * sc); b[5] = (short)f2bf(v1.y * sc);
                    b[6] = (short)f2bf(v1.z * sc); b[7] = (short)f2bf(v1.w * sc);
                    bf[g][c][kt] = b;
                }
            }
        }
        float cc[4] = {0.f, 0.f, 0.f, 0.f};
        const int hrow = l >> 2;                       // A row m=l <- h[l>>2]
        const int hsw  = (16 * q) ^ (16 * hrow);
        const float* preBase = wv ? &pre1[0][0][0][0][0] : &pre0[0][0][0][0][0];
        char* ring = (char*)(wv ? (void*)h1u : (void*)h0u);
        const int mask = wv ? 1 : 15;

        for (int s = 0; s < NSLOT; ++s) {
            BAR();
            const bool act = wv ? (s >= 2) : (s < 64);
            if (act) {
                const int u_  = wv ? (s - 2) : s;      // logical slot
                const int base_t = SS * u_;
                const float* pb0 = preBase + (u_ & 1) * 8192 + q * 256;
#pragma unroll
                for (int tau = 0; tau < SS; ++tau) {
                    const int t = base_t + tau;
                    // h(t-1) A-frags from ring
                    const char* hb = ring + ((t - 1) & mask) * 640 + hrow * 160;
                    const short8 a0 = *(const short8*)(hb + hsw);
                    const short8 a1 = *(const short8*)(hb + 64 + hsw);
                    // pre(t): 16 b32 broadcast reads (2-way banks)
                    const float* pp = pb0 + tau * 1024;
                    float y[4][4];
#pragma unroll
                    for (int g = 0; g < 4; ++g)
#pragma unroll
                        for (int w = 0; w < 4; ++w)
                            y[g][w] = pp[g * 64 + ((16 * w + l) ^ (16 * q))];
                    // recurrent GEMM: 32 MFMA, 16 independent 2-chains
#pragma unroll
                    for (int c = 0; c < 4; ++c)
#pragma unroll
                        for (int g = 0; g < 4; ++g) {
                            f32x4 acc = MFMA(a1, bf[g][c][1],
                                             MFMA(a0, bf[g][c][0], z4, 0, 0, 0),
                                             0, 0, 0);
                            y[g][c] += acc[0];
                        }
                    // 4 cells/lane (row q, units 16w+l) + swizzled h write
                    char* wb = ring + (t & mask) * 640 + q * 160;
#pragma unroll
                    for (int w = 0; w < 4; ++w) {
                        const float y0 = y[0][w], y1 = y[1][w];
                        const float y2 = y[2][w], y3 = y[3][w];
                        const float Ef = exp2f_(y1);
                        const float Ei = exp2f_(y0);
                        const float Eg = exp2f_(fminf(y2, 80.f));
                        const float sf = __builtin_amdgcn_rcpf(1.f + Ef);
                        const float rd = __builtin_amdgcn_rcpf((1.f + Ei) * (1.f + Eg));
                        cc[w] = sf * cc[w] + (Eg - 1.f) * rd;
                        const float Ec = exp2f_(fminf(cc[w] * K2, 80.f));
                        const float Eo = exp2f_(y3);
                        const float r2 = __builtin_amdgcn_rcpf((1.f + Eo) * (1.f + Ec));
                        union { float f; unsigned u; } hv; hv.f = (Ec - 1.f) * r2;
                        const ushort hval = (ushort)((hv.u + 0x8000u) >> 16);
                        *(ushort*)(wb + ((32 * w + 2 * l) ^ (16 * q))) = hval;
                    }
                }
            }
        }
    } else {
        // ================= coop wave (owns n-blocks c0, c0+1) =================
        const int c0 = 2 * (wv - 2);
        short8 wi0[4][2][2], wi1[4][2][2];   // [g][ci][kt]: 128 VGPR total
        float  bv0[4][2], bv1[4][2];
#pragma unroll
        for (int g = 0; g < 4; ++g) {
            const float sc = (g == 2) ? K2 : -LOG2E;
#pragma unroll
            for (int ci = 0; ci < 2; ++ci) {
                const int col = 64 * g + 16 * (c0 + ci) + l;
                bv0[g][ci] = (b_ih0[col] + b_hh0[col]) * sc;
                bv1[g][ci] = (b_ih1[col] + b_hh1[col]) * sc;
#pragma unroll
                for (int kt = 0; kt < 2; ++kt) {
                    const int ko = 32 * kt + 8 * q;
#define LDW(dst, W)                                                           \
                    { const float4 v0 = *(const float4*)(W + col * 64 + ko);  \
                      const float4 v1 = *(const float4*)(W + col * 64 + ko + 4); \
                      short8 b;                                               \
                      b[0]=(short)f2bf(v0.x*sc); b[1]=(short)f2bf(v0.y*sc);   \
                      b[2]=(short)f2bf(v0.z*sc); b[3]=(short)f2bf(v0.w*sc);   \
                      b[4]=(short)f2bf(v1.x*sc); b[5]=(short)f2bf(v1.y*sc);   \
                      b[6]=(short)f2bf(v1.z*sc); b[7]=(short)f2bf(v1.w*sc);   \
                      dst = b; }
                    LDW(wi0[g][ci][kt], w_ih0)
                    LDW(wi1[g][ci][kt], w_ih1)
#undef LDW
                }
            }
        }
        // x A-pack: lane supplies A row m=l -> (tau_l = l>>2, row = l&3)
        const int xrow = l & 3, xtau = l >> 2;
        const size_t xbase = ((size_t)(b0 + xrow) * TT) * 64 + 8 * q;

// pre0 for slot S_+1 (t in [8(S_+1), 8(S_+1)+8))
#define COOP_PRE0(S_)                                                         \
        {                                                                     \
            const int buf = ((S_) + 1) & 1;                                   \
            const int t0 = SS * ((S_) + 1);                                   \
            float* dst0 = &pre0[buf][0][0][0][0];                             \
            _Pragma("unroll")                                                 \
            for (int hh = 0; hh < 2; ++hh) {                                  \
                const float* px = x + xbase + (size_t)(t0 + 4 * hh + xtau) * 64; \
                const float4 v0 = *(const float4*)px;                         \
                const float4 v1 = *(const float4*)(px + 4);                   \
                const float4 v2 = *(const float4*)(px + 32);                  \
                const float4 v3 = *(const float4*)(px + 36);                  \
                const short8 xa0 = pack8(v0, v1), xa1 = pack8(v2, v3);        \
                _Pragma("unroll")                                             \
                for (int ci = 0; ci < 2; ++ci)                                \
                    _Pragma("unroll")                                         \
                    for (int g = 0; g < 4; ++g) {                             \
                        const float bv_ = bv0[g][ci];                         \
                        f32x4 acc = (f32x4){bv_, bv_, bv_, bv_};              \
                        acc = MFMA(xa0, wi0[g][ci][0], acc, 0, 0, 0);         \
                        acc = MFMA(xa1, wi0[g][ci][1], acc, 0, 0, 0);         \
                        const int uu = 16 * (c0 + ci) + l;                    \
                        float* dd = dst0 + (4 * hh + q) * 1024 + g * 64;      \
                        dd[0 * 256 + (uu ^ 0)]  = acc[0];                     \
                        dd[1 * 256 + (uu ^ 16)] = acc[1];                     \
                        dd[2 * 256 + (uu ^ 32)] = acc[2];                     \
                        dd[3 * 256 + (uu ^ 48)] = acc[3];                     \
                    }                                                         \
            }                                                                 \
        }

// pre1 for L1-slot S_-1 (t in [8(S_-1), 8S_)), h0 from ring
#define COOP_PRE1(S_)                                                         \
        {                                                                     \
            const int buf = ((S_) - 1) & 1;                                   \
            const int t1 = SS * ((S_) - 1);                                   \
            float* dst1 = &pre1[buf][0][0][0][0];                             \
            const int sw2 = (16 * q) ^ (16 * xrow);                           \
            _Pragma("unroll")                                                 \
            for (int hh = 0; hh < 2; ++hh) {                                  \
                const int tt = t1 + 4 * hh + xtau;                            \
                const char* hp = (const char*)h0u + (tt & 15) * 640 + xrow * 160; \
                const short8 ha0 = *(const short8*)(hp + sw2);                \
                const short8 ha1 = *(const short8*)(hp + 64 + sw2);           \
                _Pragma("unroll")                                             \
                for (int ci = 0; ci < 2; ++ci)                                \
                    _Pragma("unroll")                                         \
                    for (int g = 0; g < 4; ++g) {                             \
                        const float bv_ = bv1[g][ci];                         \
                        f32x4 acc = (f32x4){bv_, bv_, bv_, bv_};              \
                        acc = MFMA(ha0, wi1[g][ci][0], acc, 0, 0, 0);         \
                        acc = MFMA(ha1, wi1[g][ci][1], acc, 0, 0, 0);         \
                        const int uu = 16 * (c0 + ci) + l;                    \
                        float* dd = dst1 + (4 * hh + q) * 1024 + g * 64;      \
                        dd[0 * 256 + (uu ^ 0)]  = acc[0];                     \
                        dd[1 * 256 + (uu ^ 16)] = acc[1];                     \
                        dd[2 * 256 + (uu ^ 32)] = acc[2];                     \
                        dd[3 * 256 + (uu ^ 48)] = acc[3];                     \
                    }                                                         \
            }                                                                 \
        }

        COOP_PRE0(-1)                     // prologue: pre0 for slot 0
        for (int s = 0; s < NSLOT; ++s) {
            BAR();
            if (s < 63) COOP_PRE0(s)
            if (s >= 1 && s <= 64) COOP_PRE1(s)
        }
#undef COOP_PRE0
#undef COOP_PRE1
    }

    BAR();
    // FC + softplus on h1(511) = h1u slot 1 (swizzled rows); 128 outputs
    if (tid < MM * OO) {
        const int row = tid >> 5, o = tid & 31;
        float a = fc_b[o];
#pragma unroll
        for (int j = 0; j < 64; ++j) {
            const ushort hv = *(const ushort*)((const char*)h1u + 640
                              + row * 160 + ((2 * j) ^ (16 * row)));
            a = fmaf(fc_w[o * 64 + j], bf2f(hv), a);
        }
        out[(size_t)(b0 + row) * OO + o] =
            fmaxf(a, 0.0f) + log1pf(__expf(-fabsf(a)));   // stable softplus
    }
}

extern "C" void kernel_launch(void* const* d_in, const int* in_sizes, int n_in,
                              void* d_out, int out_size, void* d_ws, size_t ws_size,
                              hipStream_t stream) {
    const float* x     = (const float*)d_in[0];
    const float* w_ih0 = (const float*)d_in[1];
    const float* w_hh0 = (const float*)d_in[2];
    const float* b_ih0 = (const float*)d_in[3];
    const float* b_hh0 = (const float*)d_in[4];
    const float* w_ih1 = (const float*)d_in[5];
    const float* w_hh1 = (const float*)d_in[6];
    const float* b_ih1 = (const float*)d_in[7];
    const float* b_hh1 = (const float*)d_in[8];
    const float* fc_w  = (const float*)d_in[9];
    const float* fc_b  = (const float*)d_in[10];
    float* out = (float*)d_out;

    lstm_pc<<<dim3(NBLK), dim3(256), 0, stream>>>(
        x, w_ih0, w_hh0, b_ih0, b_hh0,
        w_ih1, w_hh1, b_ih1, b_hh1, fc_w, fc_b, out);
}